// Round 1
// baseline (594.970 us; speedup 1.0000x reference)
//
#include <hip/hip_runtime.h>
#include <math.h>

#define NQ 12
#define DIM 4096
#define NGATES 36
#define NGRP 12

// ---- compile-time circuit plan: CNOTs folded into GF(2) index maps ----
// Storage map M: logical index i lives at physical index M(i). CNOT(bc<-ctrl, bt<-tgt)
// updates M <- M*C (column bc ^= column bt), M^-1 <- C*M^-1 (row bt ^= row bc).
// A 1q gate on logical bit b becomes: pair (j, j^m) with m = M*e_b, "1"-element
// selected by parity(j & sel), sel = row b of M^-1. Measurement parity likewise.
struct Group {
  unsigned combo[8];        // XOR offsets for the 8 octet slots (slot bit i <-> gate i of group)
  unsigned s1, s2, s3;      // selectors of the 3 gates
  unsigned lA, lB, lC;      // low-masks for inserting 3 zero pivot bits (ascending)
};
struct Plan2 {
  Group grp[NGRP];
  unsigned zsel[NQ];
};

constexpr Plan2 make_plan() {
  Plan2 P{};
  unsigned Mcol[NQ] = {}, Minv[NQ] = {};
  for (int i = 0; i < NQ; ++i) { Mcol[i] = 1u << i; Minv[i] = 1u << i; }
  unsigned gm[NGATES] = {}, gs[NGATES] = {};
  int g = 0;
  for (int L = 0; L < 3; ++L) {
    for (int q = 0; q < NQ; ++q) { int b = NQ - 1 - q; gm[g] = Mcol[b]; gs[g] = Minv[b]; ++g; }
    for (int q = 0; q < NQ; ++q) {
      int bc = NQ - 1 - q, bt = NQ - 1 - ((q + 1) % NQ);
      Mcol[bc] ^= Mcol[bt];   // M <- M*C
      Minv[bt] ^= Minv[bc];   // M^-1 <- C*M^-1
    }
  }
  for (int i = 0; i < NGRP; ++i) {
    unsigned m1 = gm[3*i], m2 = gm[3*i+1], m3 = gm[3*i+2];
    P.grp[i].s1 = gs[3*i]; P.grp[i].s2 = gs[3*i+1]; P.grp[i].s3 = gs[3*i+2];
    for (int d = 0; d < 8; ++d) {
      unsigned c = 0;
      if (d & 1) c ^= m1;
      if (d & 2) c ^= m2;
      if (d & 4) c ^= m3;
      P.grp[i].combo[d] = c;
    }
    // Gaussian elimination to find 3 independent pivot bits for coset enumeration
    unsigned a = m1, b = m2, c = m3;
    unsigned p1 = a & (0u - a);
    if (b & p1) b ^= a;
    if (c & p1) c ^= a;
    unsigned p2 = b & (0u - b);
    if (c & p2) c ^= b;
    unsigned p3 = c & (0u - c);
    unsigned q1 = p1, q2 = p2, q3 = p3, tmp = 0;
    if (q1 > q2) { tmp = q1; q1 = q2; q2 = tmp; }
    if (q2 > q3) { tmp = q2; q2 = q3; q3 = tmp; }
    if (q1 > q2) { tmp = q1; q1 = q2; q2 = tmp; }
    P.grp[i].lA = q1 - 1u; P.grp[i].lB = q2 - 1u; P.grp[i].lC = q3 - 1u;
  }
  for (int q = 0; q < NQ; ++q) P.zsel[q] = Minv[NQ - 1 - q];
  return P;
}

__constant__ Plan2 d_plan = make_plan();

// LDS bank-conflict swizzle (bijection on [0,4096))
__device__ __forceinline__ int sw(int j) { return j ^ (j >> 6); }

__global__ __launch_bounds__(256) void qc_kernel(
    const float* __restrict__ x, const float* __restrict__ params,
    float* __restrict__ out) {
  __shared__ float2 sst[DIM];        // 32 KB state (re,im)
  __shared__ float su[NGATES * 8];   // fused gate matrices
  __shared__ float sred[64];

  const int t = threadIdx.x;
  const int row = blockIdx.x;

  // ---- fused U = RZ*RY*RX per (layer,qubit); threads 0..35 ----
  if (t < NGATES) {
    float h1 = params[3*t+0]*0.5f, h2 = params[3*t+1]*0.5f, h3 = params[3*t+2]*0.5f;
    float c1 = cosf(h1), s1 = sinf(h1);
    float c2 = cosf(h2), s2 = sinf(h2);
    float c3 = cosf(h3), s3 = sinf(h3);
    // A = RY*RX
    float a00r =  c2*c1, a00i =  s2*s1;
    float a01r = -s2*c1, a01i = -c2*s1;
    float a10r =  s2*c1, a10i = -c2*s1;
    float a11r =  c2*c1, a11i = -s2*s1;
    // row0 *= exp(-i h3), row1 *= exp(+i h3)
    float* u = &su[t*8];
    u[0] = c3*a00r + s3*a00i;  u[1] = c3*a00i - s3*a00r;
    u[2] = c3*a01r + s3*a01i;  u[3] = c3*a01i - s3*a01r;
    u[4] = c3*a10r - s3*a10i;  u[5] = c3*a10i + s3*a10r;
    u[6] = c3*a11r - s3*a11i;  u[7] = c3*a11i + s3*a11r;
  }

  // ---- load x row, sum of squares (normalization folded into epilogue) ----
  const float4* x4 = (const float4*)(x + (size_t)row * DIM);
  float ssq = 0.f;
#pragma unroll
  for (int k = 0; k < 4; ++k) {
    float4 a = x4[t + 256*k];
    int j = 4*(t + 256*k);
    sst[sw(j)]   = make_float2(a.x, 0.f);
    sst[sw(j+1)] = make_float2(a.y, 0.f);
    sst[sw(j+2)] = make_float2(a.z, 0.f);
    sst[sw(j+3)] = make_float2(a.w, 0.f);
    ssq += a.x*a.x + a.y*a.y + a.z*a.z + a.w*a.w;
  }
#pragma unroll
  for (int off = 32; off > 0; off >>= 1) ssq += __shfl_down(ssq, off, 64);
  if ((t & 63) == 0) sred[t >> 6] = ssq;
  __syncthreads();

  // ---- 12 groups of 3 generalized-bit gates; one LDS round-trip per group ----
  for (int grp = 0; grp < NGRP; ++grp) {
    const unsigned s1 = d_plan.grp[grp].s1;
    const unsigned s2 = d_plan.grp[grp].s2;
    const unsigned s3 = d_plan.grp[grp].s3;
    const unsigned lA = d_plan.grp[grp].lA;
    const unsigned lB = d_plan.grp[grp].lB;
    const unsigned lC = d_plan.grp[grp].lC;
    unsigned cb[8];
#pragma unroll
    for (int d = 0; d < 8; ++d) cb[d] = d_plan.grp[grp].combo[d];
    float uu[24];
#pragma unroll
    for (int i = 0; i < 24; ++i) uu[i] = su[grp*24 + i];

#pragma unroll
    for (int oo = 0; oo < 2; ++oo) {
      unsigned r = (unsigned)t + 256u*oo;          // 512 octets / block
      // insert zero bits at the 3 pivot positions (ascending)
      unsigned j = ((r & ~lA) << 1) | (r & lA);
      j = ((j & ~lB) << 1) | (j & lB);
      j = ((j & ~lC) << 1) | (j & lC);
      // relabel base so slot d has parity_i = d_i exactly (no runtime coeff selects)
      unsigned adj = 0;
      adj ^= (__popc(j & s1) & 1) ? cb[1] : 0u;
      adj ^= (__popc(j & s2) & 1) ? cb[2] : 0u;
      adj ^= (__popc(j & s3) & 1) ? cb[4] : 0u;
      j ^= adj;
      int idx[8];
      float ar[8], ai[8];
#pragma unroll
      for (int d = 0; d < 8; ++d) idx[d] = sw((int)(j ^ cb[d]));
#pragma unroll
      for (int d = 0; d < 8; ++d) { float2 v = sst[idx[d]]; ar[d] = v.x; ai[d] = v.y; }

      auto pair2 = [&](int i0, int i1, const float* u) {
        float a0r = ar[i0], a0i = ai[i0], a1r = ar[i1], a1i = ai[i1];
        ar[i0] = u[0]*a0r - u[1]*a0i + u[2]*a1r - u[3]*a1i;
        ai[i0] = u[0]*a0i + u[1]*a0r + u[2]*a1i + u[3]*a1r;
        ar[i1] = u[4]*a0r - u[5]*a0i + u[6]*a1r - u[7]*a1i;
        ai[i1] = u[4]*a0i + u[5]*a0r + u[6]*a1i + u[7]*a1r;
      };
      // gate 1: slot-bit 0; gate 2: slot-bit 1; gate 3: slot-bit 2 (circuit order)
      pair2(0,1,uu);    pair2(2,3,uu);    pair2(4,5,uu);    pair2(6,7,uu);
      pair2(0,2,uu+8);  pair2(1,3,uu+8);  pair2(4,6,uu+8);  pair2(5,7,uu+8);
      pair2(0,4,uu+16); pair2(1,5,uu+16); pair2(2,6,uu+16); pair2(3,7,uu+16);

#pragma unroll
      for (int d = 0; d < 8; ++d) sst[idx[d]] = make_float2(ar[d], ai[d]);
    }
    __syncthreads();
  }

  // ---- measurement: <Z_q> via parity masks, block reduce, divide by ||x||^2 ----
  float zs[NQ];
#pragma unroll
  for (int q = 0; q < NQ; ++q) zs[q] = 0.f;
#pragma unroll
  for (int k = 0; k < 16; ++k) {
    int j = t + 256*k;
    float2 v = sst[sw(j)];
    float pj = v.x*v.x + v.y*v.y;
#pragma unroll
    for (int q = 0; q < NQ; ++q) {
      zs[q] += (__popc(j & (int)d_plan.zsel[q]) & 1) ? -pj : pj;
    }
  }
#pragma unroll
  for (int q = 0; q < NQ; ++q) {
    float v = zs[q];
#pragma unroll
    for (int off = 32; off > 0; off >>= 1) v += __shfl_down(v, off, 64);
    if ((t & 63) == 0) sred[4 + (t >> 6)*NQ + q] = v;
  }
  __syncthreads();
  if (t < NQ) {
    float tot = sred[4+t] + sred[4+NQ+t] + sred[4+2*NQ+t] + sred[4+3*NQ+t];
    float den = sred[0] + sred[1] + sred[2] + sred[3];
    out[(size_t)row*NQ + t] = tot / den;
  }
}

extern "C" void kernel_launch(void* const* d_in, const int* in_sizes, int n_in,
                              void* d_out, int out_size, void* d_ws, size_t ws_size,
                              hipStream_t stream) {
  const float* x = (const float*)d_in[0];
  const float* params = (const float*)d_in[1];
  float* out = (float*)d_out;
  const int nrows = in_sizes[0] / DIM;   // 8192
  qc_kernel<<<dim3(nrows), dim3(256), 0, stream>>>(x, params, out);
}